// Round 11
// baseline (455.461 us; speedup 1.0000x reference)
//
#include <hip/hip_runtime.h>
#include <hip/hip_fp16.h>

#define SDIM 1024

typedef _Float16 f16;
typedef _Float16 f16x2v __attribute__((ext_vector_type(2)));
typedef _Float16 f16x8 __attribute__((ext_vector_type(8)));
typedef __attribute__((ext_vector_type(4))) float f32x4;

union FragH { unsigned int u[4]; f16x8 f; };
union H2U  { unsigned int u; __half2 h; f16x2v v; };

// V0: trans-free poly gelu (13 pk slots). V1: passthrough g=t (skeleton floor).
template<int V>
__device__ __forceinline__ unsigned int addgelu_pair(unsigned int au, unsigned int bu) {
    const __half2 kC5  = __float2half2_rn(-0.006912f);
    const __half2 kC4  = __float2half2_rn( 0.019336f);
    const __half2 kC3  = __float2half2_rn(-0.040316f);
    const __half2 kC2  = __float2half2_rn( 0.090220f);
    const __half2 kC1  = __float2half2_rn(-0.185452f);
    const __half2 kC0  = __float2half2_rn( 0.455649f);
    const __half2 kXA  = __float2half2_rn( 0.2222222f);
    const __half2 kXB  = __float2half2_rn(-1.0f);
    const __half2 kHalf= __float2half2_rn( 0.5f);
    const f16x2v vHi = { (f16)3.0f, (f16)3.0f };
    const f16x2v vLo = { (f16)-3.0f, (f16)-3.0f };
    H2U A, B, T, C, G;
    A.u = au; B.u = bu;
    __half2 t  = __hadd2(A.h, B.h);
    if (V == 1) { T.h = t; return T.u; }
    T.h = t;
    C.v = __builtin_elementwise_min(__builtin_elementwise_max(T.v, vLo), vHi);
    __half2 tc = C.h;
    __half2 s  = __hmul2(tc, tc);
    __half2 x  = __hfma2(s, kXA, kXB);
    __half2 w  = __hfma2(kC5, x, kC4);
    w = __hfma2(w, x, kC3);
    w = __hfma2(w, x, kC2);
    w = __hfma2(w, x, kC1);
    w = __hfma2(w, x, kC0);
    __half2 m  = __hmul2(tc, w);
    __half2 sg = __hfma2(m, kHalf, kHalf);
    G.h = __hmul2(t, sg);
    return G.u;
}

// ---------------- Kernel 1 ----------------
__global__ __launch_bounds__(256) void compute_uv(
    const float* __restrict__ x, const float* __restrict__ Wc,
    const float* __restrict__ bc, const float* __restrict__ W1,
    const float* __restrict__ b1, f16* __restrict__ u, f16* __restrict__ v)
{
    __shared__ float xrow[4 * 1024];
    __shared__ float part[4 * 8 * 32];
    __shared__ float xc[4 * 32];
    const int tid = threadIdx.x;
    const size_t bs0 = (size_t)blockIdx.x * 4;

    const float4* xin = (const float4*)(x + bs0 * 1024);
    #pragma unroll
    for (int it = 0; it < 4; ++it)
        ((float4*)xrow)[it * 256 + tid] = xin[it * 256 + tid];
    __syncthreads();
    {
        const int c = tid & 31, p = tid >> 5;
        float acc[4] = {0.f, 0.f, 0.f, 0.f};
        #pragma unroll 4
        for (int dd = 0; dd < 128; ++dd) {
            const int d = p * 128 + dd;
            const float wv = Wc[d * 32 + c];
            #pragma unroll
            for (int r = 0; r < 4; ++r)
                acc[r] = __builtin_fmaf(xrow[r * 1024 + d], wv, acc[r]);
        }
        #pragma unroll
        for (int r = 0; r < 4; ++r)
            part[r * 256 + p * 32 + c] = acc[r];
    }
    __syncthreads();
    if (tid < 128) {
        const int r = tid >> 5, c = tid & 31;
        float s = bc[c];
        #pragma unroll
        for (int p = 0; p < 8; ++p) s += part[r * 256 + p * 32 + c];
        xc[r * 32 + c] = s;
    }
    __syncthreads();
    {
        const int h = tid & 63;
        const int rr = tid >> 6;
        float ua = b1[h], va = 0.0f;
        #pragma unroll
        for (int cc = 0; cc < 32; ++cc) {
            const float xv = xc[rr * 32 + cc];
            ua = __builtin_fmaf(xv, W1[cc * 64 + h], ua);
            va = __builtin_fmaf(xv, W1[(32 + cc) * 64 + h], va);
        }
        u[(bs0 + rr) * 64 + h] = (f16)ua;
        v[(bs0 + rr) * 64 + h] = (f16)va;
    }
}

// shared per-lane setup macro for kernel-2 family
#define PRG_SETUP(IBR)                                                            \
    const int tid  = threadIdx.x;                                                 \
    const int lane = tid & 63;                                                    \
    const int w    = tid >> 6;                                                    \
    const int jb   = blockIdx.x * 64;                                             \
    const int ib   = blockIdx.y * (IBR);                                          \
    const int b    = blockIdx.z;                                                  \
    const int lg = lane >> 4;                                                     \
    const int lr = lane & 15;                                                     \
    const int k0 = lg * 8;                                                        \
    const int jA = jb + w * 16 + lr;                                              \
    const f16* vp = v + ((size_t)(b * SDIM + jA) * 64);                           \
    const uint4 vlo = *(const uint4*)(vp + k0);                                   \
    const uint4 vhi = *(const uint4*)(vp + k0 + 32);                              \
    FragH w2lo, w2hi;                                                             \
    _Pragma("unroll")                                                             \
    for (int e = 0; e < 4; ++e) {                                                 \
        H2U a, c;                                                                 \
        a.h = __floats2half2_rn(W2[(k0 + 2*e) * 16 + lr],      W2[(k0 + 2*e + 1) * 16 + lr]);      \
        c.h = __floats2half2_rn(W2[(k0 + 32 + 2*e) * 16 + lr], W2[(k0 + 32 + 2*e + 1) * 16 + lr]); \
        w2lo.u[e] = a.u;                                                          \
        w2hi.u[e] = c.u;                                                          \
    }                                                                             \
    const float b2h = b2[lr];

#define GELU_MFMA(V, il, accv)                                                    \
    {                                                                             \
        const uint4 alo = *(const uint4*)&u_lds[il][k0];                          \
        const uint4 ahi = *(const uint4*)&u_lds[il][k0 + 32];                     \
        FragH glo, ghi;                                                           \
        glo.u[0] = addgelu_pair<V>(alo.x, vlo.x);                                 \
        glo.u[1] = addgelu_pair<V>(alo.y, vlo.y);                                 \
        glo.u[2] = addgelu_pair<V>(alo.z, vlo.z);                                 \
        glo.u[3] = addgelu_pair<V>(alo.w, vlo.w);                                 \
        ghi.u[0] = addgelu_pair<V>(ahi.x, vhi.x);                                 \
        ghi.u[1] = addgelu_pair<V>(ahi.y, vhi.y);                                 \
        ghi.u[2] = addgelu_pair<V>(ahi.z, vhi.z);                                 \
        ghi.u[3] = addgelu_pair<V>(ahi.w, vhi.w);                                 \
        f32x4 acc_ = {b2h, b2h, b2h, b2h};                                        \
        acc_ = __builtin_amdgcn_mfma_f32_16x16x32_f16(glo.f, w2lo.f, acc_, 0, 0, 0); \
        acc_ = __builtin_amdgcn_mfma_f32_16x16x32_f16(ghi.f, w2hi.f, acc_, 0, 0, 0); \
        accv = acc_;                                                              \
    }

// ---- Variant A/D/C: scatter stores (D col = h, 16x64B segments per store) ----
template<int V>
__global__ __launch_bounds__(256, 2) void prg_scatter(
    const f16* __restrict__ u, const f16* __restrict__ v,
    const float* __restrict__ W2, const float* __restrict__ b2,
    float* __restrict__ out, int reps)
{
    __shared__ f16 u_lds[32][64];
    PRG_SETUP(32)
    {
        const int row = tid >> 3;
        const int col = (tid & 7) * 8;
        *(uint4*)&u_lds[row][col] =
            *(const uint4*)(u + ((size_t)(b * SDIM + ib + row) * 64 + col));
    }
    __syncthreads();
    float* ob = out + ((size_t)(b * 16 + lr) * SDIM + ib) * SDIM + (jb + w * 16 + lg * 4);
    for (int rep = 0; rep < reps; ++rep) {
        #pragma unroll 2
        for (int il = 0; il < 32; ++il) {
            f32x4 acc;
            GELU_MFMA(V, il, acc)
            *(float4*)(ob + (size_t)il * SDIM) = *(float4*)&acc;
        }
    }
}

// ---- Variant A: R10 structure (16-i tile, 2048 blocks) ----
__global__ __launch_bounds__(256) void prg_scatter16(
    const f16* __restrict__ u, const f16* __restrict__ v,
    const float* __restrict__ W2, const float* __restrict__ b2,
    float* __restrict__ out, int reps)
{
    __shared__ f16 u_lds[16][64];
    PRG_SETUP(16)
    if (tid < 128) {
        const int row = tid >> 3;
        const int col = (tid & 7) * 8;
        *(uint4*)&u_lds[row][col] =
            *(const uint4*)(u + ((size_t)(b * SDIM + ib + row) * 64 + col));
    }
    __syncthreads();
    float* ob = out + ((size_t)(b * 16 + lr) * SDIM + ib) * SDIM + (jb + w * 16 + lg * 4);
    for (int rep = 0; rep < reps; ++rep) {
        #pragma unroll 4
        for (int il = 0; il < 16; ++il) {
            f32x4 acc;
            GELU_MFMA(0, il, acc)
            *(float4*)(ob + (size_t)il * SDIM) = *(float4*)&acc;
        }
    }
}

// ---- Variant B + final: LDS-transpose epilogue (4x256B segments per store) ----
__global__ __launch_bounds__(256, 2) void prg_xpose(
    const f16* __restrict__ u, const f16* __restrict__ v,
    const float* __restrict__ W2, const float* __restrict__ b2,
    float* __restrict__ out, int reps)
{
    __shared__ f16   u_lds[32][64];
    __shared__ float o_lds[4][16][64];
    PRG_SETUP(32)
    {
        const int row = tid >> 3;
        const int col = (tid & 7) * 8;
        *(uint4*)&u_lds[row][col] =
            *(const uint4*)(u + ((size_t)(b * SDIM + ib + row) * 64 + col));
    }
    const int jg = lane & 15;
    const int hq = (lane >> 4) & 3;
    const int wslot = ((w << 2) | lg) ^ lr;
    __syncthreads();

    for (int rep = 0; rep < reps; ++rep) {
        float* pg = out + (((size_t)(b * 16 + hq * 4) * SDIM) + (ib + w)) * SDIM + jb + jg * 4;
        for (int g = 0; g < 8; ++g) {
            f32x4 acc[4];
            #pragma unroll
            for (int q = 0; q < 4; ++q) {
                const int il = g * 4 + q;
                GELU_MFMA(0, il, acc[q])
            }
            __syncthreads();
            #pragma unroll
            for (int q = 0; q < 4; ++q)
                *(float4*)&o_lds[q][lr][wslot << 2] = *(float4*)&acc[q];
            __syncthreads();
            #pragma unroll
            for (int it = 0; it < 4; ++it) {
                const int rslot = jg ^ (hq * 4 + it);
                const float4 val = *(const float4*)&o_lds[w][hq * 4 + it][rslot << 2];
                *(float4*)(pg + (size_t)it * SDIM * SDIM) = val;
            }
            pg += 4 * SDIM;
        }
    }
}

extern "C" void kernel_launch(void* const* d_in, const int* in_sizes, int n_in,
                              void* d_out, int out_size, void* d_ws, size_t ws_size,
                              hipStream_t stream) {
    const float* x  = (const float*)d_in[0];
    const float* Wc = (const float*)d_in[1];
    const float* bc = (const float*)d_in[2];
    const float* W1 = (const float*)d_in[3];
    const float* b1 = (const float*)d_in[4];
    const float* W2 = (const float*)d_in[5];
    const float* b2 = (const float*)d_in[6];
    float* out = (float*)d_out;

    f16* u = (f16*)d_ws;
    f16* v = u + 2 * SDIM * 64;

    compute_uv<<<dim3(512), dim3(256), 0, stream>>>(x, Wc, bc, W1, b1, u, v);

    // Diagnostics (garbage values in out, overwritten by the final pass; reps sized
    // so each dispatch clears the ~84us harness fills into the top-5 counter rows):
    prg_scatter16<<<dim3(16, 64, 2), dim3(256), 0, stream>>>(u, v, W2, b2, out, 3);  // A
    prg_scatter<0><<<dim3(16, 32, 2), dim3(256), 0, stream>>>(u, v, W2, b2, out, 3); // D
    prg_scatter<1><<<dim3(16, 32, 2), dim3(256), 0, stream>>>(u, v, W2, b2, out, 6); // C (skeleton)
    prg_xpose<<<dim3(16, 32, 2), dim3(256), 0, stream>>>(u, v, W2, b2, out, 3);      // B
    // Final correct pass:
    prg_xpose<<<dim3(16, 32, 2), dim3(256), 0, stream>>>(u, v, W2, b2, out, 1);
}

// Round 12
// 49.760 us; speedup vs baseline: 9.1531x; 9.1531x over previous
//
#include <hip/hip_runtime.h>
#include <hip/hip_fp16.h>

#define SDIM 1024

typedef _Float16 f16;
typedef _Float16 f16x2v __attribute__((ext_vector_type(2)));
typedef _Float16 f16x8 __attribute__((ext_vector_type(8)));
typedef __attribute__((ext_vector_type(4))) float f32x4;

union FragH { unsigned int u[4]; f16x8 f; uint4 q; };
union H2U  { unsigned int u; __half2 h; f16x2v v; };

// trans-free poly gelu (13 pk-VALU slots, 0 trans). See R10 notes for the fit.
__device__ __forceinline__ unsigned int addgelu_pair(unsigned int au, unsigned int bu) {
    const __half2 kC5  = __float2half2_rn(-0.006912f);
    const __half2 kC4  = __float2half2_rn( 0.019336f);
    const __half2 kC3  = __float2half2_rn(-0.040316f);
    const __half2 kC2  = __float2half2_rn( 0.090220f);
    const __half2 kC1  = __float2half2_rn(-0.185452f);
    const __half2 kC0  = __float2half2_rn( 0.455649f);
    const __half2 kXA  = __float2half2_rn( 0.2222222f);
    const __half2 kXB  = __float2half2_rn(-1.0f);
    const __half2 kHalf= __float2half2_rn( 0.5f);
    const f16x2v vHi = { (f16)3.0f, (f16)3.0f };
    const f16x2v vLo = { (f16)-3.0f, (f16)-3.0f };
    H2U A, B, T, C, G;
    A.u = au; B.u = bu;
    __half2 t  = __hadd2(A.h, B.h);
    T.h = t;
    C.v = __builtin_elementwise_min(__builtin_elementwise_max(T.v, vLo), vHi);
    __half2 tc = C.h;
    __half2 s  = __hmul2(tc, tc);
    __half2 x  = __hfma2(s, kXA, kXB);
    __half2 w  = __hfma2(kC5, x, kC4);
    w = __hfma2(w, x, kC3);
    w = __hfma2(w, x, kC2);
    w = __hfma2(w, x, kC1);
    w = __hfma2(w, x, kC0);
    __half2 m  = __hmul2(tc, w);
    __half2 sg = __hfma2(m, kHalf, kHalf);
    G.h = __hmul2(t, sg);
    return G.u;
}

// ---------------- Kernel 1: u,v (f16) + W2h = W2^T in f16 [16h][64k] ----------------
__global__ __launch_bounds__(256) void compute_uv(
    const float* __restrict__ x, const float* __restrict__ Wc,
    const float* __restrict__ bc, const float* __restrict__ W1,
    const float* __restrict__ b1, const float* __restrict__ W2,
    f16* __restrict__ u, f16* __restrict__ v, f16* __restrict__ W2h)
{
    __shared__ float xrow[4 * 1024];
    __shared__ float part[4 * 8 * 32];
    __shared__ float xc[4 * 32];
    const int tid = threadIdx.x;
    const size_t bs0 = (size_t)blockIdx.x * 4;

    if (blockIdx.x == 0) {   // one-time W2 transpose+convert (1024 elems)
        #pragma unroll
        for (int e = 0; e < 4; ++e) {
            const int flat = tid * 4 + e;          // flat = h*64 + k
            const int h = flat >> 6, k = flat & 63;
            W2h[flat] = (f16)W2[k * 16 + h];
        }
    }

    const float4* xin = (const float4*)(x + bs0 * 1024);
    #pragma unroll
    for (int it = 0; it < 4; ++it)
        ((float4*)xrow)[it * 256 + tid] = xin[it * 256 + tid];
    __syncthreads();
    {
        const int c = tid & 31, p = tid >> 5;
        float acc[4] = {0.f, 0.f, 0.f, 0.f};
        #pragma unroll 4
        for (int dd = 0; dd < 128; ++dd) {
            const int d = p * 128 + dd;
            const float wv = Wc[d * 32 + c];
            #pragma unroll
            for (int r = 0; r < 4; ++r)
                acc[r] = __builtin_fmaf(xrow[r * 1024 + d], wv, acc[r]);
        }
        #pragma unroll
        for (int r = 0; r < 4; ++r)
            part[r * 256 + p * 32 + c] = acc[r];
    }
    __syncthreads();
    if (tid < 128) {
        const int r = tid >> 5, c = tid & 31;
        float s = bc[c];
        #pragma unroll
        for (int p = 0; p < 8; ++p) s += part[r * 256 + p * 32 + c];
        xc[r * 32 + c] = s;
    }
    __syncthreads();
    {
        const int h = tid & 63;
        const int rr = tid >> 6;
        float ua = b1[h], va = 0.0f;
        #pragma unroll
        for (int cc = 0; cc < 32; ++cc) {
            const float xv = xc[rr * 32 + cc];
            ua = __builtin_fmaf(xv, W1[cc * 64 + h], ua);
            va = __builtin_fmaf(xv, W1[(32 + cc) * 64 + h], va);
        }
        u[(bs0 + rr) * 64 + h] = (f16)ua;
        v[(bs0 + rr) * 64 + h] = (f16)va;
    }
}

// ---------------- Kernel 2: out[b,h,i,j] = sum_k gelu(u[i,k]+v[j,k])*W2[k,h] + b2[h] --
// 32i x 32j tile, 4 waves: wave w -> i-half (w>>1), j-half (w&1); 16 il per wave.
// Grid (32,32,2) = 2048 blocks = 8 blocks/CU; launch_bounds(256,6) caps VGPR for
// 6 waves/SIMD. Group-of-4 il: 4 acc quads live -> 4-store bursts -> vmcnt(<=3)
// waits instead of full drains; other waves' VALU hides each wave's store drain.
__global__ __launch_bounds__(256, 6) void prg_main(
    const f16* __restrict__ u, const f16* __restrict__ v,
    const f16* __restrict__ W2h, const float* __restrict__ b2,
    float* __restrict__ out)
{
    const int tid  = threadIdx.x;
    const int lane = tid & 63;
    const int w    = tid >> 6;
    const int jb   = blockIdx.x * 32;
    const int ib   = blockIdx.y * 32;
    const int b    = blockIdx.z;

    __shared__ f16 u_lds[32][64];   // 4 KB

    {
        const int row = tid >> 3;
        const int col = (tid & 7) * 8;
        *(uint4*)&u_lds[row][col] =
            *(const uint4*)(u + ((size_t)(b * SDIM + ib + row) * 64 + col));
    }

    const int lg = lane >> 4;   // k-group 0..3
    const int lr = lane & 15;   // A/D row-col index: A row (j), D col (h)
    const int k0 = lg * 8;
    const int jw = jb + (w & 1) * 16;   // wave's j-base
    const int iw = (w >> 1) * 16;       // wave's i-base within tile

    const f16* vp = v + ((size_t)(b * SDIM + jw + lr) * 64);
    const uint4 vlo = *(const uint4*)(vp + k0);
    const uint4 vhi = *(const uint4*)(vp + k0 + 32);

    FragH w2lo, w2hi;
    w2lo.q = *(const uint4*)(W2h + lr * 64 + k0);
    w2hi.q = *(const uint4*)(W2h + lr * 64 + k0 + 32);

    const float b2h = b2[lr];

    __syncthreads();

    float* ob = out + ((size_t)(b * 16 + lr) * SDIM + (ib + iw)) * SDIM + jw + lg * 4;

    #pragma unroll
    for (int g = 0; g < 4; ++g) {
        f32x4 acc[4];
        #pragma unroll
        for (int q = 0; q < 4; ++q) {
            const int il = iw + g * 4 + q;
            const uint4 alo = *(const uint4*)&u_lds[il][k0];
            const uint4 ahi = *(const uint4*)&u_lds[il][k0 + 32];
            FragH glo, ghi;
            glo.u[0] = addgelu_pair(alo.x, vlo.x);
            glo.u[1] = addgelu_pair(alo.y, vlo.y);
            glo.u[2] = addgelu_pair(alo.z, vlo.z);
            glo.u[3] = addgelu_pair(alo.w, vlo.w);
            ghi.u[0] = addgelu_pair(ahi.x, vhi.x);
            ghi.u[1] = addgelu_pair(ahi.y, vhi.y);
            ghi.u[2] = addgelu_pair(ahi.z, vhi.z);
            ghi.u[3] = addgelu_pair(ahi.w, vhi.w);
            f32x4 a = {b2h, b2h, b2h, b2h};
            a = __builtin_amdgcn_mfma_f32_16x16x32_f16(glo.f, w2lo.f, a, 0, 0, 0);
            a = __builtin_amdgcn_mfma_f32_16x16x32_f16(ghi.f, w2hi.f, a, 0, 0, 0);
            acc[q] = a;
        }
        #pragma unroll
        for (int q = 0; q < 4; ++q)
            *(float4*)(ob + (size_t)(g * 4 + q) * SDIM) = *(float4*)&acc[q];
    }
}

extern "C" void kernel_launch(void* const* d_in, const int* in_sizes, int n_in,
                              void* d_out, int out_size, void* d_ws, size_t ws_size,
                              hipStream_t stream) {
    const float* x  = (const float*)d_in[0];
    const float* Wc = (const float*)d_in[1];
    const float* bc = (const float*)d_in[2];
    const float* W1 = (const float*)d_in[3];
    const float* b1 = (const float*)d_in[4];
    const float* W2 = (const float*)d_in[5];
    const float* b2 = (const float*)d_in[6];
    float* out = (float*)d_out;

    f16* u   = (f16*)d_ws;                 // 256 KB
    f16* v   = u + 2 * SDIM * 64;          // 256 KB
    f16* W2h = v + 2 * SDIM * 64;          // 2 KB

    compute_uv<<<dim3(512), dim3(256), 0, stream>>>(x, Wc, bc, W1, b1, W2, u, v, W2h);
    prg_main<<<dim3(32, 32, 2), dim3(256), 0, stream>>>(u, v, W2h, b2, out);
}